// Round 7
// baseline (3668.644 us; speedup 1.0000x reference)
//
#include <hip/hip_runtime.h>
#include <hip/hip_fp16.h>
#include <math.h>

#define NT 1024

typedef _Float16 h2v __attribute__((ext_vector_type(2)));
union H8 { uint4 u; h2v h[4]; };

__device__ __forceinline__ float sigf(float x)   { return 1.0f / (1.0f + __expf(-x)); }
__device__ __forceinline__ float tanhf_(float x) { return 1.0f - 2.0f / (1.0f + __expf(2.0f * x)); }
__device__ __forceinline__ float dot4(float4 a, float4 b) {
    return a.x * b.x + a.y * b.y + a.z * b.z + a.w * b.w;
}
__device__ __forceinline__ float red16(float v) {
    v += __shfl_xor(v, 1); v += __shfl_xor(v, 2);
    v += __shfl_xor(v, 4); v += __shfl_xor(v, 8);
    return v;
}
__device__ __forceinline__ float red64(float v) {
    v += __shfl_xor(v, 1);  v += __shfl_xor(v, 2);  v += __shfl_xor(v, 4);
    v += __shfl_xor(v, 8);  v += __shfl_xor(v, 16); v += __shfl_xor(v, 32);
    return v;
}
__device__ __forceinline__ float dot2h(h2v a, h2v b, float c) {
#if __has_builtin(__builtin_amdgcn_fdot2)
    return __builtin_amdgcn_fdot2(a, b, c, false);
#else
    return c + (float)a[0] * (float)b[0] + (float)a[1] * (float)b[1];
#endif
}

// LLC-coherent read (bypasses L1/L2; no cache flush).
__device__ __forceinline__ float exr(const float* p) {
    return __hip_atomic_load(p, __ATOMIC_RELAXED, __HIP_MEMORY_SCOPE_AGENT);
}

// Split fence-free group barrier. All exchange writes come from wave 0
// (tid<64) via atomicExch (executes at LLC); tid0's s_waitcnt vmcnt(0)
// covers the whole wave's outstanding ops before the signal.
__device__ __forceinline__ void xsig(unsigned* ctr) {
    if (threadIdx.x == 0) {
        asm volatile("s_waitcnt vmcnt(0)" ::: "memory");
        __hip_atomic_fetch_add(ctr, 1u, __ATOMIC_RELAXED, __HIP_MEMORY_SCOPE_AGENT);
    }
}
__device__ __forceinline__ void xwait(unsigned* ctr, unsigned target) {
    if (threadIdx.x == 0) {
        while (__hip_atomic_load(ctr, __ATOMIC_RELAXED, __HIP_MEMORY_SCOPE_AGENT) < target)
            __builtin_amdgcn_s_sleep(1);
    }
    __syncthreads();
}

// ws half-offsets (permuted-packed fp16 weights)
#define OFF_RA   0          // aw1[:, 0:512]          64 x 512
#define OFF_RE0  32768      // [wihe0|whhe0|pad]      1024 x 384
#define OFF_RE1  425984     // [wihe1|whhe1]          1024 x 512
#define OFF_RDW1 950272     // dw1[:, 0:512]          256 x 512
#define OFF_RD0  1081344    // [wihd0[:,0:256]|whhd0] 1024 x 512
#define OFF_RDT  1605632    // wihd0[:, 256]          1024
#define OFF_RD1  1606656    // [wihd1|whhd1]          1024 x 512
#define TOT_H    2130944

// K=512 GEMV: 16 lanes/row, 4 rows/wave-iter. First PF iters consume
// pre-loaded weights (register prefetch issued during exchange wait).
template<int ITERS, int PF, bool BIAS, bool DT>
__device__ __forceinline__ void gemv512p(const __half* __restrict__ W,
                                         const uint4* __restrict__ pre,
                                         const __half* __restrict__ act,
                                         const float* __restrict__ bias,
                                         const __half* __restrict__ rdt, float dts,
                                         float* __restrict__ outg,
                                         int jBase, int ljBase) {
    const int lane = threadIdx.x & 63;
    const int q = lane & 15, g = lane >> 4;
    H8 a0, a1, a2, a3;
    a0.u = *(const uint4*)(act + 8 * q);
    a1.u = *(const uint4*)(act + 8 * q + 128);
    a2.u = *(const uint4*)(act + 8 * q + 256);
    a3.u = *(const uint4*)(act + 8 * q + 384);
    #pragma unroll
    for (int it = 0; it < ITERS; ++it) {
        const int j = jBase + it * 4 + g;
        H8 w0, w1, w2, w3;
        if (it < PF) {
            w0.u = pre[it * 4 + 0]; w1.u = pre[it * 4 + 1];
            w2.u = pre[it * 4 + 2]; w3.u = pre[it * 4 + 3];
        } else {
            const uint4* wp = (const uint4*)(W + ((size_t)j << 9) + 32 * q);
            w0.u = wp[0]; w1.u = wp[1]; w2.u = wp[2]; w3.u = wp[3];
        }
        float s0 = 0.f, s1 = 0.f;
        #pragma unroll
        for (int i = 0; i < 4; ++i) {
            s0 = dot2h(w0.h[i], a0.h[i], s0);
            s1 = dot2h(w1.h[i], a1.h[i], s1);
            s0 = dot2h(w2.h[i], a2.h[i], s0);
            s1 = dot2h(w3.h[i], a3.h[i], s1);
        }
        float s = s0 + s1;
        s += __shfl_xor(s, 1); s += __shfl_xor(s, 2);
        s += __shfl_xor(s, 4); s += __shfl_xor(s, 8);
        if (q == 0) {
            if (DT) s += dts * (float)rdt[j];
            outg[ljBase + it * 4 + g] = BIAS ? s + bias[j] : s;
        }
    }
}

// Register prefetch of the first PF row-groups of a K=512 tile.
template<int PF>
__device__ __forceinline__ void pf512(const __half* __restrict__ W, int jBase,
                                      uint4* pre) {
    const int lane = threadIdx.x & 63;
    const int q = lane & 15, g = lane >> 4;
    #pragma unroll
    for (int it = 0; it < PF; ++it) {
        const int j = jBase + it * 4 + g;
        const uint4* wp = (const uint4*)(W + ((size_t)j << 9) + 32 * q);
        pre[it * 4 + 0] = wp[0]; pre[it * 4 + 1] = wp[1];
        pre[it * 4 + 2] = wp[2]; pre[it * 4 + 3] = wp[3];
    }
}

// K=384 GEMV
template<int ITERS>
__device__ __forceinline__ void gemv384x(const __half* __restrict__ W,
                                         const __half* __restrict__ act,
                                         const float* __restrict__ bias,
                                         float* __restrict__ outg,
                                         int jBase, int ljBase) {
    const int lane = threadIdx.x & 63;
    const int q = lane & 15, g = lane >> 4;
    H8 a0, a1, a2;
    a0.u = *(const uint4*)(act + 8 * q);
    a1.u = *(const uint4*)(act + 8 * q + 128);
    a2.u = *(const uint4*)(act + 8 * q + 256);
    #pragma unroll 2
    for (int it = 0; it < ITERS; ++it) {
        const int j = jBase + it * 4 + g;
        const uint4* wp = (const uint4*)(W + (size_t)j * 384 + 24 * q);
        H8 w0, w1, w2;
        w0.u = wp[0]; w1.u = wp[1]; w2.u = wp[2];
        float s0 = 0.f, s1 = 0.f;
        #pragma unroll
        for (int i = 0; i < 4; ++i) {
            s0 = dot2h(w0.h[i], a0.h[i], s0);
            s1 = dot2h(w1.h[i], a1.h[i], s1);
            s0 = dot2h(w2.h[i], a2.h[i], s0);
        }
        float s = s0 + s1;
        s += __shfl_xor(s, 1); s += __shfl_xor(s, 2);
        s += __shfl_xor(s, 4); s += __shfl_xor(s, 8);
        if (q == 0) outg[ljBase + it * 4 + g] = s + bias[j];
    }
}

// ---------------- v7 LDS layout (floats) ----------------
#define M_HEXP  0        // 16384
#define M_XET   16384    // 4352 (64 x 68)
#define M_GSL   20736    // 256
#define M_HCT   20992    // 256
#define M_SCORE 21312    // 64
#define M_AS    21376    // 64
#define M_C0    21440    // 64
#define M_C1    21504    // 64
#define M_HC1F  21568    // 256
#define M_DECIN 21824    // 64
#define M_PARTF 21888    // 256
#define M_BE0   22144    // 1024
#define M_BE1   23168    // 1024
#define M_BD0   24192    // 1024
#define M_BD1   25216    // 1024
#define M_AHC   26240    // 256 f = 512 halfs [h1|c1]
#define M_AE0   26496    // 192 f = 384 halfs [x_in|h0|0]
#define M_AHH   26688    // 256 f = 512 halfs [h0|h1]
#define M_AD0   26944    // 256 f = 512 halfs [partial|h0]
#define M_RDT   27200    // 512 f = 1024 halfs
#define M_TOT   27712

// ===== v7: 4 blocks/batch, fence-free LLC exchange, prefetch-hidden waits ==
extern "C" __global__ void __launch_bounds__(NT)
attn_lstm_v7(const float* __restrict__ inp,  const __half* __restrict__ wsh,
             float* __restrict__ h0x, float* __restrict__ h1x,
             unsigned* __restrict__ barc,
             const float* __restrict__ bihe, const float* __restrict__ bhhe,
             const float* __restrict__ bihd, const float* __restrict__ bhhd,
             const float* __restrict__ aw1,  const float* __restrict__ ab1,
             const float* __restrict__ aw2,
             const float* __restrict__ dw1,  const float* __restrict__ db1,
             const float* __restrict__ dw2,
             const float* __restrict__ pw,   const float* __restrict__ pb,
             float* __restrict__ out)
{
    extern __shared__ __align__(16) float sm[];
    float* hexp   = sm + M_HEXP;
    float* xeT    = sm + M_XET;
    float* gsl    = sm + M_GSL;
    float* hctL   = sm + M_HCT;
    float* scoreS = sm + M_SCORE;
    float* aS     = sm + M_AS;
    float* c0L    = sm + M_C0;
    float* c1L    = sm + M_C1;
    float* hc1f   = sm + M_HC1F;
    float* decin  = sm + M_DECIN;
    float* partF  = sm + M_PARTF;
    float* bE0    = sm + M_BE0;
    float* bE1    = sm + M_BE1;
    float* bD0    = sm + M_BD0;
    float* bD1    = sm + M_BD1;
    __half* aHC   = (__half*)(sm + M_AHC);
    __half* aE0   = (__half*)(sm + M_AE0);
    __half* aHH   = (__half*)(sm + M_AHH);
    __half* aD0   = (__half*)(sm + M_AD0);
    __half* rdtL  = (__half*)(sm + M_RDT);

    const __half* RA   = wsh + OFF_RA;
    const __half* RE0  = wsh + OFF_RE0;
    const __half* RE1  = wsh + OFF_RE1;
    const __half* RDW1 = wsh + OFF_RDW1;
    const __half* RD0  = wsh + OFF_RD0;
    const __half* RD1  = wsh + OFF_RD1;

    const int tid = threadIdx.x;
    const int b   = blockIdx.x >> 2;
    const int co  = blockIdx.x & 3;
    const int w   = tid >> 6;
    unsigned* ctr = barc + (b << 4);
    unsigned  ph  = 0;

    // ---- init ----
    if (tid < 64) { c0L[tid] = 0.f; c1L[tid] = 0.f; }
    for (int i = tid; i < 960; i += NT) sm[M_AHC + i] = 0.0f;   // aHC..aD0
    if (tid < 512) sm[M_RDT + tid] = ((const float*)(wsh + OFF_RDT))[tid];
    {
        int j = tid;
        bE0[j] = bihe[j]        + bhhe[j];
        bE1[j] = bihe[1024 + j] + bhhe[1024 + j];
        bD0[j] = bihd[j]        + bhhd[j];
        bD1[j] = bihd[1024 + j] + bhhd[1024 + j];
    }
    const float* ib = inp + b * (64 * 65);
    for (int i = tid; i < 4096; i += NT) {
        int t = i & 63, e = i >> 6;
        xeT[e * 68 + t] = ib[t * 65 + 1 + e];
    }
    if (tid < 64) decin[tid] = ib[tid * 65];
    __syncthreads();

    const int g16 = tid >> 4, q16 = tid & 15;
    const int gg = w >> 2, cb = (w & 3) << 4;
    const int jB  = gg * 256 + co * 64 + cb;   // global weight row base (split)
    const int ljB = gg * 64 + cb;              // local gate-slice base

    // ---- encoder attention P (input part + bias, fp32 one-time) -> regs ----
    float Preg[4], w2r[4];
    #pragma unroll
    for (int jj = 0; jj < 4; ++jj) {
        int j = q16 + 16 * jj;
        w2r[jj] = aw2[j];
        float acc = ab1[j];
        const float4* w4 = (const float4*)(aw1 + j * 576 + 512);
        const float4* x4 = (const float4*)(xeT + g16 * 68);
        #pragma unroll 4
        for (int k = 0; k < 16; ++k) acc += dot4(w4[k], x4[k]);
        Preg[jj] = acc;
    }

    uint4 preA[4];   // E1 tile (full: ITERS=1)
    uint4 preW[8];   // E6/D7 half-tile
    uint4 preD[8];   // D1 half-tile

    // ================= encoder: 64 steps, 2 exchanges each =================
    pf512<1>(RA, w * 4, preA);
    for (int t = 0; t < 64; ++t) {
        const int p = t & 1;
        float* h0b = h0x + p * 16384 + b * 256;
        float* h1b = h1x + p * 32768 + b * 512;
        // E1 (replicated, fully prefetched): hct[j<64] = [h1;c1] . aw1[j,0:512)
        gemv512p<1, 1, false, false>(RA, preA, aHC, nullptr, nullptr, 0.f,
                                     hctL, w * 4, w * 4);
        __syncthreads();
        // E2: score[e]
        {
            float s = 0.f;
            #pragma unroll
            for (int jj = 0; jj < 4; ++jj)
                s += tanhf_(Preg[jj] + hctL[q16 + 16 * jj]) * w2r[jj];
            s = red16(s);
            if (q16 == 0) scoreS[g16] = s;
        }
        __syncthreads();
        // E3: softmax + x_in
        if (tid < 64) {
            float v = scoreS[tid], m = v;
            #pragma unroll
            for (int d = 1; d < 64; d <<= 1) m = fmaxf(m, __shfl_xor(m, d));
            float ex = __expf(v - m), s = ex;
            #pragma unroll
            for (int d = 1; d < 64; d <<= 1) s += __shfl_xor(s, d);
            aE0[tid] = __float2half((ex / s) * xeT[tid * 68 + t]);
        }
        __syncthreads();
        // E4 (split): layer0 gates, own 256 rows
        gemv384x<4>(RE0, aE0, bE0, gsl, jB, ljB);
        __syncthreads();
        // E5: elementwise l0 (own 64 ch) -> exchange h0; hide wait w/ E6 pf
        if (tid < 64) {
            float cn = sigf(gsl[64 + tid]) * c0L[tid] + sigf(gsl[tid]) * tanhf_(gsl[128 + tid]);
            float hn = sigf(gsl[192 + tid]) * tanhf_(cn);
            c0L[tid] = cn;
            atomicExch(&h0b[co * 64 + tid], hn);
        }
        xsig(ctr); ++ph;
        pf512<2>(RE1, jB, preW);
        xwait(ctr, ph * 4u);
        if (tid < 256) {
            __half hh = __float2half(exr(&h0b[tid]));
            aE0[64 + tid] = hh; aHH[tid] = hh;
        }
        __syncthreads();
        // E6 (split): layer1 gates (first half prefetched)
        gemv512p<4, 2, true, false>(RE1, preW, aHH, bE1, nullptr, 0.f,
                                    gsl, jB, ljB);
        __syncthreads();
        // E7: elementwise l1 -> exchange h1,c1; hide wait w/ next-E1 pf
        if (tid < 64) {
            float cn = sigf(gsl[64 + tid]) * c1L[tid] + sigf(gsl[tid]) * tanhf_(gsl[128 + tid]);
            float hn = sigf(gsl[192 + tid]) * tanhf_(cn);
            c1L[tid] = cn;
            atomicExch(&h1b[co * 64 + tid], hn);
            atomicExch(&h1b[256 + co * 64 + tid], cn);
        }
        xsig(ctr); ++ph;
        pf512<1>(RA, w * 4, preA);
        xwait(ctr, ph * 4u);
        if (tid < 512) {
            float v = exr(&h1b[tid]);
            __half hh = __float2half(v);
            aHC[tid] = hh;
            if (tid < 256) { aHH[256 + tid] = hh; hexp[t * 256 + tid] = v; }
        }
        __syncthreads();
    }

    // ---- transition: zero recurrent state; Pd precompute -> regs ----
    if (tid < 64) { c0L[tid] = 0.f; c1L[tid] = 0.f; }
    for (int i = tid; i < 960; i += NT) sm[M_AHC + i] = 0.0f;
    __syncthreads();
    float Pdreg[16], w2dr[16];
    #pragma unroll
    for (int jj = 0; jj < 16; ++jj) {
        int j = q16 + 16 * jj;
        w2dr[jj] = dw2[j];
        float acc = db1[j];
        const float4* w4 = (const float4*)(dw1 + j * 768 + 512);
        const float4* x4 = (const float4*)(hexp + g16 * 256);
        #pragma unroll 4
        for (int k = 0; k < 64; ++k) acc += dot4(w4[k], x4[k]);
        Pdreg[jj] = acc;
    }
    __syncthreads();

    // ============ decoder: 64 steps, 2 exchanges each (D1 replicated) ======
    const int j4 = tid >> 2, q4 = tid & 3;
    pf512<2>(RDW1, w * 16, preD);
    for (int t = 0; t < 64; ++t) {
        const int p = t & 1;
        float* h0b = h0x + p * 16384 + b * 256;
        float* h1b = h1x + p * 32768 + b * 512;
        // D1 (replicated, half-prefetched): hctd[j<256] = [h1;c1].dw1[j,0:512)
        gemv512p<4, 2, false, false>(RDW1, preD, aHC, nullptr, nullptr, 0.f,
                                     hctL, w * 16, w * 16);
        __syncthreads();
        // D2: score[t']
        {
            float s = 0.f;
            #pragma unroll
            for (int jj = 0; jj < 16; ++jj)
                s += tanhf_(Pdreg[jj] + hctL[q16 + 16 * jj]) * w2dr[jj];
            s = red16(s);
            if (q16 == 0) scoreS[g16] = s;
        }
        __syncthreads();
        // D3: softmax -> aS
        if (tid < 64) {
            float v = scoreS[tid], m = v;
            #pragma unroll
            for (int d = 1; d < 64; d <<= 1) m = fmaxf(m, __shfl_xor(m, d));
            float ex = __expf(v - m), s = ex;
            #pragma unroll
            for (int d = 1; d < 64; d <<= 1) s += __shfl_xor(s, d);
            aS[tid] = ex / s;
        }
        __syncthreads();
        // D4 (replicated): partial[c]
        {
            float acc = 0.f;
            #pragma unroll 4
            for (int i = 0; i < 16; ++i) {
                int tt = q4 + 4 * i;
                acc += hexp[tt * 256 + j4] * aS[tt];
            }
            acc += __shfl_xor(acc, 1);
            acc += __shfl_xor(acc, 2);
            if (q4 == 0) { aD0[j4] = __float2half(acc); partF[j4] = acc; }
        }
        __syncthreads();
        // D5 (split): layer0 gates (+ d_t column)
        gemv512p<4, 0, true, true>(RD0, nullptr, aD0, bD0, rdtL, decin[t],
                                   gsl, jB, ljB);
        __syncthreads();
        // D6: elementwise l0 -> exchange h0; hide wait w/ D7 pf
        if (tid < 64) {
            float cn = sigf(gsl[64 + tid]) * c0L[tid] + sigf(gsl[tid]) * tanhf_(gsl[128 + tid]);
            float hn = sigf(gsl[192 + tid]) * tanhf_(cn);
            c0L[tid] = cn;
            atomicExch(&h0b[co * 64 + tid], hn);
        }
        xsig(ctr); ++ph;
        pf512<2>(RD1, jB, preW);
        xwait(ctr, ph * 4u);
        if (tid < 256) {
            __half hh = __float2half(exr(&h0b[tid]));
            aD0[256 + tid] = hh; aHH[tid] = hh;
        }
        __syncthreads();
        // D7 (split): layer1 gates (first half prefetched)
        gemv512p<4, 2, true, false>(RD1, preW, aHH, bD1, nullptr, 0.f,
                                    gsl, jB, ljB);
        __syncthreads();
        // D8: elementwise l1 -> exchange h1,c1; hide wait w/ next-D1 pf
        if (tid < 64) {
            float cn = sigf(gsl[64 + tid]) * c1L[tid] + sigf(gsl[tid]) * tanhf_(gsl[128 + tid]);
            float hn = sigf(gsl[192 + tid]) * tanhf_(cn);
            c1L[tid] = cn;
            atomicExch(&h1b[co * 64 + tid], hn);
            atomicExch(&h1b[256 + co * 64 + tid], cn);
        }
        xsig(ctr); ++ph;
        pf512<2>(RDW1, w * 16, preD);
        xwait(ctr, ph * 4u);
        if (tid < 512) {
            float v = exr(&h1b[tid]);
            __half hh = __float2half(v);
            aHC[tid] = hh;
            if (tid < 256) { aHH[256 + tid] = hh; hc1f[tid] = v; }
        }
        __syncthreads();
    }

    // ---- output (one block per b) ----
    if (co == 0 && tid < 64) {
        float acc = 0.f;
        #pragma unroll
        for (int i = 0; i < 8; ++i) {
            int k = tid + 64 * i;
            float v = (k < 256) ? hc1f[k] : partF[k - 256];
            acc += v * pw[k];
        }
        acc = red64(acc);
        if (tid == 0) out[b] = fabsf(acc + pb[0]);
    }
}

// ---------------- v5 LDS layout (fallback kernel) ----------------
#define L_HEXP   0
#define L_XET    16384
#define L_GSL    20736
#define L_HCT    21760
#define L_SCORE  22016
#define L_AS     22080
#define L_C0     22144
#define L_HC1F   22400
#define L_DECIN  22912
#define L_PARTF  22976
#define L_BE0    23232
#define L_BE1    24256
#define L_BD0    25280
#define L_BD1    26304
#define L_AHC    27328
#define L_AE0    27584
#define L_AHH    27776
#define L_AD0    28032
#define L_RDT    28288
#define L_TOT    28800

extern "C" __global__ void __launch_bounds__(NT)
attn_lstm_v5(const float* __restrict__ inp,  const __half* __restrict__ wsh,
             const float* __restrict__ bihe, const float* __restrict__ bhhe,
             const float* __restrict__ bihd, const float* __restrict__ bhhd,
             const float* __restrict__ aw1,  const float* __restrict__ ab1,
             const float* __restrict__ aw2,
             const float* __restrict__ dw1,  const float* __restrict__ db1,
             const float* __restrict__ dw2,
             const float* __restrict__ pw,   const float* __restrict__ pb,
             float* __restrict__ out)
{
    extern __shared__ __align__(16) float sm[];
    float* hexp   = sm + L_HEXP;
    float* xeT    = sm + L_XET;
    float* gsl    = sm + L_GSL;
    float* hctL   = sm + L_HCT;
    float* scoreS = sm + L_SCORE;
    float* aS     = sm + L_AS;
    float* c0L    = sm + L_C0;
    float* hc1f   = sm + L_HC1F;
    float* decin  = sm + L_DECIN;
    float* partF  = sm + L_PARTF;
    float* bE0    = sm + L_BE0;
    float* bE1    = sm + L_BE1;
    float* bD0    = sm + L_BD0;
    float* bD1    = sm + L_BD1;
    __half* aHC   = (__half*)(sm + L_AHC);
    __half* aE0   = (__half*)(sm + L_AE0);
    __half* aHH   = (__half*)(sm + L_AHH);
    __half* aD0   = (__half*)(sm + L_AD0);
    __half* rdtL  = (__half*)(sm + L_RDT);

    const __half* RA   = wsh + OFF_RA;
    const __half* RE0  = wsh + OFF_RE0;
    const __half* RE1  = wsh + OFF_RE1;
    const __half* RDW1 = wsh + OFF_RDW1;
    const __half* RD0  = wsh + OFF_RD0;
    const __half* RD1  = wsh + OFF_RD1;

    const int b   = blockIdx.x;
    const int tid = threadIdx.x;
    const int w   = tid >> 6;

    for (int i = tid; i < (L_BE0 - L_C0); i += NT) sm[L_C0 + i] = 0.0f;
    for (int i = tid; i < (L_RDT - L_AHC); i += NT) sm[L_AHC + i] = 0.0f;
    if (tid < 512) sm[L_RDT + tid] = ((const float*)(wsh + OFF_RDT))[tid];
    {
        int j = tid;
        bE0[j] = bihe[j]        + bhhe[j];
        bE1[j] = bihe[1024 + j] + bhhe[1024 + j];
        bD0[j] = bihd[j]        + bhhd[j];
        bD1[j] = bihd[1024 + j] + bhhd[1024 + j];
    }
    const float* ib = inp + b * (64 * 65);
    for (int i = tid; i < 4096; i += NT) {
        int t = i & 63, e = i >> 6;
        xeT[e * 68 + t] = ib[t * 65 + 1 + e];
    }
    if (tid < 64) decin[tid] = ib[tid * 65];
    __syncthreads();

    const int g16 = tid >> 4, q16 = tid & 15;

    float Preg[4], w2r[4];
    #pragma unroll
    for (int jj = 0; jj < 4; ++jj) {
        int j = q16 + 16 * jj;
        w2r[jj] = aw2[j];
        float acc = ab1[j];
        const float4* w4 = (const float4*)(aw1 + j * 576 + 512);
        const float4* x4 = (const float4*)(xeT + g16 * 68);
        #pragma unroll 4
        for (int k = 0; k < 16; ++k) acc += dot4(w4[k], x4[k]);
        Preg[jj] = acc;
    }

    for (int t = 0; t < 64; ++t) {
        gemv512p<1, 0, false, false>(RA, nullptr, aHC, nullptr, nullptr, 0.f, hctL, w * 4, w * 4);
        __syncthreads();
        {
            float s = 0.f;
            #pragma unroll
            for (int jj = 0; jj < 4; ++jj)
                s += tanhf_(Preg[jj] + hctL[q16 + 16 * jj]) * w2r[jj];
            s = red16(s);
            if (q16 == 0) scoreS[g16] = s;
        }
        __syncthreads();
        if (tid < 64) {
            float v = scoreS[tid], m = v;
            #pragma unroll
            for (int d = 1; d < 64; d <<= 1) m = fmaxf(m, __shfl_xor(m, d));
            float ex = __expf(v - m), s = ex;
            #pragma unroll
            for (int d = 1; d < 64; d <<= 1) s += __shfl_xor(s, d);
            aE0[tid] = __float2half((ex / s) * xeT[tid * 68 + t]);
        }
        __syncthreads();
        gemv384x<16>(RE0, aE0, bE0, gsl, w * 64, w * 64);
        __syncthreads();
        if (tid < 256) {
            float cn = sigf(gsl[256 + tid]) * c0L[tid] + sigf(gsl[tid]) * tanhf_(gsl[512 + tid]);
            float hn = sigf(gsl[768 + tid]) * tanhf_(cn);
            c0L[tid] = cn;
            __half hh = __float2half(hn);
            aE0[64 + tid] = hh; aHH[tid] = hh;
        }
        __syncthreads();
        gemv512p<16, 0, true, false>(RE1, nullptr, aHH, bE1, nullptr, 0.f, gsl, w * 64, w * 64);
        __syncthreads();
        if (tid < 256) {
            float cp = hc1f[256 + tid];
            float cn = sigf(gsl[256 + tid]) * cp + sigf(gsl[tid]) * tanhf_(gsl[512 + tid]);
            float hn = sigf(gsl[768 + tid]) * tanhf_(cn);
            hc1f[tid] = hn; hc1f[256 + tid] = cn;
            __half hh = __float2half(hn);
            aHC[tid] = hh; aHC[256 + tid] = __float2half(cn);
            aHH[256 + tid] = hh;
            hexp[t * 256 + tid] = hn;
        }
        __syncthreads();
    }

    if (tid < 256) { c0L[tid] = 0.0f; hc1f[tid] = 0.0f; hc1f[256 + tid] = 0.0f; }
    for (int i = tid; i < (L_RDT - L_AHC); i += NT) sm[L_AHC + i] = 0.0f;
    __syncthreads();
    float Pdreg[16], w2dr[16];
    #pragma unroll
    for (int jj = 0; jj < 16; ++jj) {
        int j = q16 + 16 * jj;
        w2dr[jj] = dw2[j];
        float acc = db1[j];
        const float4* w4 = (const float4*)(dw1 + j * 768 + 512);
        const float4* x4 = (const float4*)(hexp + g16 * 256);
        #pragma unroll 4
        for (int k = 0; k < 64; ++k) acc += dot4(w4[k], x4[k]);
        Pdreg[jj] = acc;
    }
    __syncthreads();

    const int j4 = tid >> 2, q4 = tid & 3;
    for (int t = 0; t < 64; ++t) {
        gemv512p<4, 0, false, false>(RDW1, nullptr, aHC, nullptr, nullptr, 0.f, hctL, w * 16, w * 16);
        __syncthreads();
        {
            float s = 0.f;
            #pragma unroll
            for (int jj = 0; jj < 16; ++jj)
                s += tanhf_(Pdreg[jj] + hctL[q16 + 16 * jj]) * w2dr[jj];
            s = red16(s);
            if (q16 == 0) scoreS[g16] = s;
        }
        __syncthreads();
        if (tid < 64) {
            float v = scoreS[tid], m = v;
            #pragma unroll
            for (int d = 1; d < 64; d <<= 1) m = fmaxf(m, __shfl_xor(m, d));
            float ex = __expf(v - m), s = ex;
            #pragma unroll
            for (int d = 1; d < 64; d <<= 1) s += __shfl_xor(s, d);
            aS[tid] = ex / s;
        }
        __syncthreads();
        {
            float acc = 0.f;
            #pragma unroll 4
            for (int i = 0; i < 16; ++i) {
                int tt = q4 + 4 * i;
                acc += hexp[tt * 256 + j4] * aS[tt];
            }
            acc += __shfl_xor(acc, 1);
            acc += __shfl_xor(acc, 2);
            if (q4 == 0) { aD0[j4] = __float2half(acc); partF[j4] = acc; }
        }
        __syncthreads();
        gemv512p<16, 0, true, true>(RD0, nullptr, aD0, bD0, rdtL, decin[t], gsl, w * 64, w * 64);
        __syncthreads();
        if (tid < 256) {
            float cn = sigf(gsl[256 + tid]) * c0L[tid] + sigf(gsl[tid]) * tanhf_(gsl[512 + tid]);
            float hn = sigf(gsl[768 + tid]) * tanhf_(cn);
            c0L[tid] = cn;
            __half hh = __float2half(hn);
            aD0[256 + tid] = hh; aHH[tid] = hh;
        }
        __syncthreads();
        gemv512p<16, 0, true, false>(RD1, nullptr, aHH, bD1, nullptr, 0.f, gsl, w * 64, w * 64);
        __syncthreads();
        if (tid < 256) {
            float cp = hc1f[256 + tid];
            float cn = sigf(gsl[256 + tid]) * cp + sigf(gsl[tid]) * tanhf_(gsl[512 + tid]);
            float hn = sigf(gsl[768 + tid]) * tanhf_(cn);
            hc1f[tid] = hn; hc1f[256 + tid] = cn;
            __half hh = __float2half(hn);
            aHC[tid] = hh; aHC[256 + tid] = __float2half(cn);
            aHH[256 + tid] = hh;
        }
        __syncthreads();
    }

    if (tid < 64) {
        float acc = 0.f;
        #pragma unroll
        for (int i = 0; i < 8; ++i) {
            int k = tid + 64 * i;
            float v = (k < 256) ? hc1f[k] : partF[k - 256];
            acc += v * pw[k];
        }
        acc = red64(acc);
        if (tid == 0) out[b] = fabsf(acc + pb[0]);
    }
}

// ---- fp16 permuted repack (unchanged) ----
extern "C" __global__ void repack16b(const float* __restrict__ wihe0,
                                     const float* __restrict__ wihe1,
                                     const float* __restrict__ whhe,
                                     const float* __restrict__ wihd0,
                                     const float* __restrict__ wihd1,
                                     const float* __restrict__ whhd,
                                     const float* __restrict__ aw1,
                                     const float* __restrict__ dw1,
                                     __half* __restrict__ ws) {
    int idx = blockIdx.x * blockDim.x + threadIdx.x;
    if (idx >= TOT_H) return;
    int o = idx; float v;
    if (o < 32768) {
        int j = o >> 9, p = o & 511;
        int q = p >> 5, r = p & 31, c = r >> 3, e = r & 7;
        int k = 8 * q + 128 * c + e;
        v = aw1[j * 576 + k];
        ws[OFF_RA + o] = __float2half_rn(v); return;
    }
    o -= 32768;
    if (o < 393216) {
        int j = o / 384, p = o - j * 384;
        int q = p / 24, r = p - q * 24, c = r >> 3, e = r & 7;
        int k = 8 * q + 128 * c + e;
        v = (k < 64) ? wihe0[j * 64 + k] : (k < 320 ? whhe[j * 256 + (k - 64)] : 0.0f);
        ws[OFF_RE0 + o] = __float2half_rn(v); return;
    }
    o -= 393216;
    if (o < 524288) {
        int j = o >> 9, p = o & 511;
        int q = p >> 5, r = p & 31, c = r >> 3, e = r & 7;
        int k = 8 * q + 128 * c + e;
        v = (k < 256) ? wihe1[j * 256 + k] : whhe[262144 + j * 256 + (k - 256)];
        ws[OFF_RE1 + o] = __float2half_rn(v); return;
    }
    o -= 524288;
    if (o < 131072) {
        int j = o >> 9, p = o & 511;
        int q = p >> 5, r = p & 31, c = r >> 3, e = r & 7;
        int k = 8 * q + 128 * c + e;
        v = dw1[j * 768 + k];
        ws[OFF_RDW1 + o] = __float2half_rn(v); return;
    }
    o -= 131072;
    if (o < 524288) {
        int j = o >> 9, p = o & 511;
        int q = p >> 5, r = p & 31, c = r >> 3, e = r & 7;
        int k = 8 * q + 128 * c + e;
        v = (k < 256) ? wihd0[j * 257 + k] : whhd[j * 256 + (k - 256)];
        ws[OFF_RD0 + o] = __float2half_rn(v); return;
    }
    o -= 524288;
    if (o < 1024) {
        v = wihd0[o * 257 + 256];
        ws[OFF_RDT + o] = __float2half_rn(v); return;
    }
    o -= 1024;
    {
        int j = o >> 9, p = o & 511;
        int q = p >> 5, r = p & 31, c = r >> 3, e = r & 7;
        int k = 8 * q + 128 * c + e;
        v = (k < 256) ? wihd1[j * 256 + k] : whhd[262144 + j * 256 + (k - 256)];
        ws[OFF_RD1 + o] = __float2half_rn(v);
    }
}

extern "C" void kernel_launch(void* const* d_in, const int* in_sizes, int n_in,
                              void* d_out, int out_size, void* d_ws, size_t ws_size,
                              hipStream_t stream) {
    const float* inp   = (const float*)d_in[0];
    const float* wihe0 = (const float*)d_in[1];
    const float* wihe1 = (const float*)d_in[2];
    const float* whhe  = (const float*)d_in[3];
    const float* bihe  = (const float*)d_in[4];
    const float* bhhe  = (const float*)d_in[5];
    const float* wihd0 = (const float*)d_in[6];
    const float* wihd1 = (const float*)d_in[7];
    const float* whhd  = (const float*)d_in[8];
    const float* bihd  = (const float*)d_in[9];
    const float* bhhd  = (const float*)d_in[10];
    const float* aw1   = (const float*)d_in[11];
    const float* ab1   = (const float*)d_in[12];
    const float* aw2   = (const float*)d_in[13];
    const float* dw1   = (const float*)d_in[14];
    const float* db1   = (const float*)d_in[15];
    const float* dw2   = (const float*)d_in[16];
    const float* pw    = (const float*)d_in[17];
    const float* pb    = (const float*)d_in[18];
    float* out = (float*)d_out;

    // ws layout (float offsets): fp16 weights occupy [0, TOT_H/2)
    const size_t EX0 = TOT_H / 2;            // 1,065,472
    const size_t H0X = EX0;                  // 2*64*256 = 32768
    const size_t H1X = EX0 + 32768;          // 2*64*512 = 65536
    const size_t CTR = EX0 + 131072;         // 64*16 uints (keep legacy offset)
    const size_t NEED7 = (CTR + 1024) * sizeof(float);

    if (ws_size >= NEED7) {
        float* ws32 = (float*)d_ws;
        __half* wsh = (__half*)d_ws;
        hipMemsetAsync((char*)d_ws + CTR * sizeof(float), 0, 4096, stream);
        repack16b<<<(TOT_H + 255) / 256, 256, 0, stream>>>(
            wihe0, wihe1, whhe, wihd0, wihd1, whhd, aw1, dw1, wsh);
        const int smem = M_TOT * 4;   // ~108 KB
        hipFuncSetAttribute((const void*)attn_lstm_v7,
                            hipFuncAttributeMaxDynamicSharedMemorySize, smem);
        attn_lstm_v7<<<256, NT, smem, stream>>>(
            inp, wsh, ws32 + H0X, ws32 + H1X,
            (unsigned*)(ws32 + CTR),
            bihe, bhhe, bihd, bhhd,
            aw1, ab1, aw2, dw1, db1, dw2, pw, pb, out);
        return;
    }

    // fallback: v5 single-block-per-batch
    if (ws_size >= (size_t)TOT_H * sizeof(__half)) {
        __half* wsh = (__half*)d_ws;
        repack16b<<<(TOT_H + 255) / 256, 256, 0, stream>>>(
            wihe0, wihe1, whhe, wihd0, wihd1, whhd, aw1, dw1, wsh);
        const int smem = L_TOT * 4;
        hipFuncSetAttribute((const void*)attn_lstm_v5,
                            hipFuncAttributeMaxDynamicSharedMemorySize, smem);
        attn_lstm_v5<<<64, NT, smem, stream>>>(
            inp, wsh, bihe, bhhe, bihd, bhhd,
            aw1, ab1, aw2, dw1, db1, dw2, pw, pb, out);
    }
}

// Round 9
// 2167.796 us; speedup vs baseline: 1.6923x; 1.6923x over previous
//
#include <hip/hip_runtime.h>
#include <hip/hip_fp16.h>
#include <math.h>

#define NT8 512
#define NT  1024

typedef _Float16 h2v __attribute__((ext_vector_type(2)));
union H8 { uint4 u; h2v h[4]; };

__device__ __forceinline__ float sigf(float x)   { return 1.0f / (1.0f + __expf(-x)); }
__device__ __forceinline__ float tanhf_(float x) { return 1.0f - 2.0f / (1.0f + __expf(2.0f * x)); }
__device__ __forceinline__ float dot4(float4 a, float4 b) {
    return a.x * b.x + a.y * b.y + a.z * b.z + a.w * b.w;
}
__device__ __forceinline__ float red16(float v) {
    v += __shfl_xor(v, 1); v += __shfl_xor(v, 2);
    v += __shfl_xor(v, 4); v += __shfl_xor(v, 8);
    return v;
}
__device__ __forceinline__ float red8(float v) {
    v += __shfl_xor(v, 1); v += __shfl_xor(v, 2); v += __shfl_xor(v, 4);
    return v;
}
__device__ __forceinline__ float red64(float v) {
    v += __shfl_xor(v, 1);  v += __shfl_xor(v, 2);  v += __shfl_xor(v, 4);
    v += __shfl_xor(v, 8);  v += __shfl_xor(v, 16); v += __shfl_xor(v, 32);
    return v;
}
__device__ __forceinline__ float dot2h(h2v a, h2v b, float c) {
#if __has_builtin(__builtin_amdgcn_fdot2)
    return __builtin_amdgcn_fdot2(a, b, c, false);
#else
    return c + (float)a[0] * (float)b[0] + (float)a[1] * (float)b[1];
#endif
}

// LLC-coherent read (bypasses L1/L2; no cache flush). Proven v6 mechanism.
__device__ __forceinline__ float exr(const float* p) {
    return __hip_atomic_load(p, __ATOMIC_RELAXED, __HIP_MEMORY_SCOPE_AGENT);
}
// Split fence-free group barrier (v6/v7-proven). Exchange writes come from
// wave 0 via atomicExch (executes at LLC); tid0's vmcnt(0) covers wave 0.
__device__ __forceinline__ void xsig(unsigned* ctr) {
    if (threadIdx.x == 0) {
        asm volatile("s_waitcnt vmcnt(0)" ::: "memory");
        __hip_atomic_fetch_add(ctr, 1u, __ATOMIC_RELAXED, __HIP_MEMORY_SCOPE_AGENT);
    }
}
__device__ __forceinline__ void xwait(unsigned* ctr, unsigned target) {
    if (threadIdx.x == 0) {
        while (__hip_atomic_load(ctr, __ATOMIC_RELAXED, __HIP_MEMORY_SCOPE_AGENT) < target)
            __builtin_amdgcn_s_sleep(1);
    }
    __syncthreads();
}

// ws half-offsets (permuted-packed fp16 weights)
#define OFF_RA   0          // aw1[:, 0:512]          64 x 512
#define OFF_RE0  32768      // [wihe0|whhe0|pad]      1024 x 384
#define OFF_RE1  425984     // [wihe1|whhe1]          1024 x 512
#define OFF_RDW1 950272     // dw1[:, 0:512]          256 x 512
#define OFF_RD0  1081344    // [wihd0[:,0:256]|whhd0] 1024 x 512
#define OFF_RDT  1605632    // wihd0[:, 256]          1024
#define OFF_RD1  1606656    // [wihd1|whhd1]          1024 x 512
#define OFF_RPD  2130944    // dw1[:, 512:768]        256 x 256 (Pd tile)
#define TOT_H2   2196480

// ---------------- v8 GEMV helpers (NT8=512: 8 waves) ----------------
// Split K=512: wave w owns local rows l = w*16 + it*4 + g (l<128);
// global j = gate*256 + co*32 + ch = ((l&0x60)<<3) + coB + (l&31).
template<int ITERS, bool BIAS, bool DT>
__device__ __forceinline__ void gemvS512(const __half* __restrict__ W,
                                         const __half* __restrict__ act,
                                         const float* __restrict__ biasF,
                                         const __half* __restrict__ rdtH, float dts,
                                         float* __restrict__ outg, int coB) {
    const int lane = threadIdx.x & 63;
    const int q = lane & 15, g = lane >> 4;
    const int w = threadIdx.x >> 6;
    H8 a0, a1, a2, a3;
    a0.u = *(const uint4*)(act + 8 * q);
    a1.u = *(const uint4*)(act + 8 * q + 128);
    a2.u = *(const uint4*)(act + 8 * q + 256);
    a3.u = *(const uint4*)(act + 8 * q + 384);
    #pragma unroll 2
    for (int it = 0; it < ITERS; ++it) {
        const int l = w * 16 + it * 4 + g;
        const int j = ((l & 0x60) << 3) + coB + (l & 31);
        const uint4* wp = (const uint4*)(W + ((size_t)j << 9) + 32 * q);
        H8 w0, w1, w2, w3;
        w0.u = wp[0]; w1.u = wp[1]; w2.u = wp[2]; w3.u = wp[3];
        float s0 = 0.f, s1 = 0.f;
        #pragma unroll
        for (int i = 0; i < 4; ++i) {
            s0 = dot2h(w0.h[i], a0.h[i], s0);
            s1 = dot2h(w1.h[i], a1.h[i], s1);
            s0 = dot2h(w2.h[i], a2.h[i], s0);
            s1 = dot2h(w3.h[i], a3.h[i], s1);
        }
        float s = red16(s0 + s1);
        if (q == 0) {
            if (DT) s += dts * (float)rdtH[l];
            outg[l] = BIAS ? s + biasF[l] : s;
        }
    }
}

// Split K=384 (encoder layer0)
template<int ITERS>
__device__ __forceinline__ void gemvS384(const __half* __restrict__ W,
                                         const __half* __restrict__ act,
                                         const float* __restrict__ biasF,
                                         float* __restrict__ outg, int coB) {
    const int lane = threadIdx.x & 63;
    const int q = lane & 15, g = lane >> 4;
    const int w = threadIdx.x >> 6;
    H8 a0, a1, a2;
    a0.u = *(const uint4*)(act + 8 * q);
    a1.u = *(const uint4*)(act + 8 * q + 128);
    a2.u = *(const uint4*)(act + 8 * q + 256);
    #pragma unroll 2
    for (int it = 0; it < ITERS; ++it) {
        const int l = w * 16 + it * 4 + g;
        const int j = ((l & 0x60) << 3) + coB + (l & 31);
        const h2v* hp = (const h2v*)(W + (size_t)j * 384 + 24 * q);
        float s0 = 0.f, s1 = 0.f;
        #pragma unroll
        for (int i = 0; i < 4; ++i) s0 = dot2h(hp[i],     a0.h[i], s0);
        #pragma unroll
        for (int i = 0; i < 4; ++i) s1 = dot2h(hp[4 + i], a1.h[i], s1);
        #pragma unroll
        for (int i = 0; i < 4; ++i) s0 = dot2h(hp[8 + i], a2.h[i], s0);
        float s = red16(s0 + s1);
        if (q == 0) outg[l] = s + biasF[l];
    }
}

// Replicated E1: rows j = w*8 + it*4 + g (64 rows), K=512
__device__ __forceinline__ void gemvE1(const __half* __restrict__ W,
                                       const __half* __restrict__ act,
                                       float* __restrict__ outg) {
    const int lane = threadIdx.x & 63;
    const int q = lane & 15, g = lane >> 4;
    const int w = threadIdx.x >> 6;
    H8 a0, a1, a2, a3;
    a0.u = *(const uint4*)(act + 8 * q);
    a1.u = *(const uint4*)(act + 8 * q + 128);
    a2.u = *(const uint4*)(act + 8 * q + 256);
    a3.u = *(const uint4*)(act + 8 * q + 384);
    #pragma unroll
    for (int it = 0; it < 2; ++it) {
        const int j = w * 8 + it * 4 + g;
        const uint4* wp = (const uint4*)(W + ((size_t)j << 9) + 32 * q);
        H8 w0, w1, w2, w3;
        w0.u = wp[0]; w1.u = wp[1]; w2.u = wp[2]; w3.u = wp[3];
        float s0 = 0.f, s1 = 0.f;
        #pragma unroll
        for (int i = 0; i < 4; ++i) {
            s0 = dot2h(w0.h[i], a0.h[i], s0);
            s1 = dot2h(w1.h[i], a1.h[i], s1);
            s0 = dot2h(w2.h[i], a2.h[i], s0);
            s1 = dot2h(w3.h[i], a3.h[i], s1);
        }
        float s = red16(s0 + s1);
        if (q == 0) outg[j] = s;
    }
}

// ---------------- v8 LDS layout (floats) ----------------
#define V8_HEXP  0        // 8192  (16384 halfs: hexp fp16)
#define V8_R     8192     // 8192  (xeT fp32 4352 in enc | PdL fp16 16384h in dec)
#define V8_GSL   16384    // 128
#define V8_HCT   16512    // 256
#define V8_SCORE 16768    // 64
#define V8_AS    16832    // 64
#define V8_C0    16896    // 32
#define V8_C1    16928    // 32
#define V8_HC1F  16960    // 256
#define V8_DECIN 17216    // 64
#define V8_PARTF 17280    // 256
#define V8_BE0   17536    // 128 (fp32)
#define V8_BE1   17664    // 128
#define V8_BD0   17792    // 128
#define V8_BD1   17920    // 128
#define V8_AHC   18048    // 256 (512h) [h1|c1]
#define V8_AE0   18304    // 192 (384h) [x_in|h0|0]
#define V8_AHH   18496    // 256 (512h) [h0|h1]
#define V8_AD0   18752    // 256 (512h) [partial|h0]
#define V8_RDT   19008    // 64  (128h)
#define V8_W2D   19072    // 256
#define V8_TMP   19328    // 32
#define V8_TOT   19360    // x4 = 77,440 B -> 2 blocks/CU

// ===== v8: 8 blocks/batch x 512 thr, 2 blocks/CU, fence-free LLC exchange ==
extern "C" __global__ void __launch_bounds__(NT8)
attn_lstm_v8(const float* __restrict__ inp,  const __half* __restrict__ wsh,
             float* __restrict__ h0x, float* __restrict__ h1x,
             float* __restrict__ hcx, unsigned* __restrict__ barc,
             const float* __restrict__ bihe, const float* __restrict__ bhhe,
             const float* __restrict__ bihd, const float* __restrict__ bhhd,
             const float* __restrict__ aw1,  const float* __restrict__ ab1,
             const float* __restrict__ aw2,  const float* __restrict__ db1,
             const float* __restrict__ dw2,
             const float* __restrict__ pw,   const float* __restrict__ pb,
             float* __restrict__ out)
{
    extern __shared__ __align__(16) float sm[];
    __half* hexp16 = (__half*)(sm + V8_HEXP);
    float*  xeT    = sm + V8_R;                 // encoder
    __half* PdL16  = (__half*)(sm + V8_R);      // decoder (overlays xeT)
    float* gsl    = sm + V8_GSL;
    float* hctL   = sm + V8_HCT;
    float* scoreS = sm + V8_SCORE;
    float* aS     = sm + V8_AS;
    float* c0L    = sm + V8_C0;
    float* c1L    = sm + V8_C1;
    float* hc1f   = sm + V8_HC1F;
    float* decin  = sm + V8_DECIN;
    float* partF  = sm + V8_PARTF;
    float* bE0f   = sm + V8_BE0;
    float* bE1f   = sm + V8_BE1;
    float* bD0f   = sm + V8_BD0;
    float* bD1f   = sm + V8_BD1;
    __half* aHC   = (__half*)(sm + V8_AHC);
    __half* aE0   = (__half*)(sm + V8_AE0);
    __half* aHH   = (__half*)(sm + V8_AHH);
    __half* aD0   = (__half*)(sm + V8_AD0);
    __half* rdtH  = (__half*)(sm + V8_RDT);
    float* w2dL   = sm + V8_W2D;
    float* tmp32  = sm + V8_TMP;

    const __half* RA   = wsh + OFF_RA;
    const __half* RE0  = wsh + OFF_RE0;
    const __half* RE1  = wsh + OFF_RE1;
    const __half* RDW1 = wsh + OFF_RDW1;
    const __half* RD0  = wsh + OFF_RD0;
    const __half* RD1  = wsh + OFF_RD1;
    const __half* RPD  = wsh + OFF_RPD;

    const int tid = threadIdx.x;
    const int b   = blockIdx.x >> 3;
    const int co  = blockIdx.x & 7;
    const int coB = co * 32;
    const int w   = tid >> 6;
    const int lane = tid & 63;
    const int q16 = lane & 15, g4 = lane >> 4;
    unsigned* ctr = barc + (b << 4);
    unsigned  ph  = 0;

    // ---- init: zero misc region, stage biases/rdt/inputs ----
    for (int i = tid; i < V8_TOT - V8_GSL; i += NT8) sm[V8_GSL + i] = 0.0f;
    const float* ib = inp + b * (64 * 65);
    for (int i = tid; i < 4096; i += NT8) {
        int t = i & 63, e = i >> 6;
        xeT[e * 68 + t] = ib[t * 65 + 1 + e];
    }
    __syncthreads();   // zeroing complete before typed writes below
    if (tid < 128) {
        int l = tid;
        int j = ((l & 0x60) << 3) + coB + (l & 31);
        bE0f[l] = bihe[j]        + bhhe[j];
        bE1f[l] = bihe[1024 + j] + bhhe[1024 + j];
        bD0f[l] = bihd[j]        + bhhd[j];
        bD1f[l] = bihd[1024 + j] + bhhd[1024 + j];
        rdtH[l] = wsh[OFF_RDT + j];
    }
    if (tid < 64) decin[tid] = ib[tid * 65];
    if (tid < 256) w2dL[tid] = dw2[tid];
    __syncthreads();

    // ---- encoder attention P (input part + bias, fp32 one-time) -> regs ----
    const int e8 = tid >> 3, q8 = tid & 7;
    float Preg[8], w2r[8];
    #pragma unroll
    for (int jj = 0; jj < 8; ++jj) {
        int j = q8 + 8 * jj;
        w2r[jj] = aw2[j];
        float acc = ab1[j];
        const float4* w4 = (const float4*)(aw1 + j * 576 + 512);
        const float4* x4 = (const float4*)(xeT + e8 * 68);
        #pragma unroll 4
        for (int k = 0; k < 16; ++k) acc += dot4(w4[k], x4[k]);
        Preg[jj] = acc;
    }

    // ================= encoder: 64 steps, 2 exchanges each =================
    for (int t = 0; t < 64; ++t) {
        const int p = t & 1;
        float* h0b = h0x + p * 16384 + b * 256;
        float* h1b = h1x + p * 32768 + b * 512;
        // E1 (replicated): hct[j<64] = [h1;c1] . RA
        gemvE1(RA, aHC, hctL);
        __syncthreads();
        // E2: score[e]
        {
            float s = 0.f;
            #pragma unroll
            for (int jj = 0; jj < 8; ++jj)
                s += tanhf_(Preg[jj] + hctL[q8 + 8 * jj]) * w2r[jj];
            s = red8(s);
            if (q8 == 0) scoreS[e8] = s;
        }
        __syncthreads();
        // E3: softmax + x_in
        if (tid < 64) {
            float v = scoreS[tid], m = v;
            #pragma unroll
            for (int d = 1; d < 64; d <<= 1) m = fmaxf(m, __shfl_xor(m, d));
            float ex = __expf(v - m), s = ex;
            #pragma unroll
            for (int d = 1; d < 64; d <<= 1) s += __shfl_xor(s, d);
            aE0[tid] = __float2half((ex / s) * xeT[tid * 68 + t]);
        }
        __syncthreads();
        // E4 (split): layer0 gates, own 128 rows
        gemvS384<4>(RE0, aE0, bE0f, gsl, coB);
        __syncthreads();
        // E5: elementwise l0 (own 32 ch) -> exchange h0
        if (tid < 32) {
            float cn = sigf(gsl[32 + tid]) * c0L[tid] + sigf(gsl[tid]) * tanhf_(gsl[64 + tid]);
            float hn = sigf(gsl[96 + tid]) * tanhf_(cn);
            c0L[tid] = cn;
            atomicExch(&h0b[coB + tid], hn);
        }
        xsig(ctr); ++ph;
        xwait(ctr, ph * 8u);
        if (tid < 256) {
            __half hh = __float2half(exr(&h0b[tid]));
            aE0[64 + tid] = hh; aHH[tid] = hh;
        }
        __syncthreads();
        // E6 (split): layer1 gates
        gemvS512<4, true, false>(RE1, aHH, bE1f, nullptr, 0.f, gsl, coB);
        __syncthreads();
        // E7: elementwise l1 -> exchange h1,c1
        if (tid < 32) {
            float cn = sigf(gsl[32 + tid]) * c1L[tid] + sigf(gsl[tid]) * tanhf_(gsl[64 + tid]);
            float hn = sigf(gsl[96 + tid]) * tanhf_(cn);
            c1L[tid] = cn;
            atomicExch(&h1b[coB + tid], hn);
            atomicExch(&h1b[256 + coB + tid], cn);
        }
        xsig(ctr); ++ph;
        xwait(ctr, ph * 8u);
        if (tid < 512) {
            float v = exr(&h1b[tid]);
            __half hh = __float2half(v);
            aHC[tid] = hh;
            if (tid < 256) { aHH[256 + tid] = hh; hexp16[t * 256 + tid] = hh; }
        }
        __syncthreads();
    }

    // ---- transition: zero recurrent state (EXACTLY aHC..aD0 = 960 floats;
    //      do NOT touch V8_RDT/V8_W2D — R8's bug) ----
    if (tid < 32) { c0L[tid] = 0.f; c1L[tid] = 0.f; }
    for (int i = tid; i < 960; i += NT8) sm[V8_AHC + i] = 0.0f;
    __syncthreads();
    // Pd (replicated): PdL16[t'][j] = db1[j] + dw1[j,512:768] . hexp[t']
    {
        #pragma unroll 1
        for (int it = 0; it < 8; ++it) {
            const int j = it * 32 + w * 4 + g4;
            const h2v* wp = (const h2v*)(RPD + ((size_t)j << 8) + 16 * q16);
            h2v w0 = wp[0], w1 = wp[1], w2 = wp[2], w3 = wp[3];
            h2v w4 = wp[4], w5 = wp[5], w6 = wp[6], w7 = wp[7];
            float dbj = db1[j];
            #pragma unroll 2
            for (int tp = 0; tp < 64; ++tp) {
                const h2v* xp = (const h2v*)(hexp16 + tp * 256 + 8 * q16);
                const h2v* yp = (const h2v*)(hexp16 + tp * 256 + 8 * q16 + 128);
                float s = 0.f;
                s = dot2h(w0, xp[0], s); s = dot2h(w1, xp[1], s);
                s = dot2h(w2, xp[2], s); s = dot2h(w3, xp[3], s);
                s = dot2h(w4, yp[0], s); s = dot2h(w5, yp[1], s);
                s = dot2h(w6, yp[2], s); s = dot2h(w7, yp[3], s);
                s = red16(s);
                if (q16 == 0) PdL16[tp * 256 + j] = __float2half(s + dbj);
            }
        }
    }
    __syncthreads();

    // ============ decoder: 64 steps, 3 exchanges each ============
    for (int t = 0; t < 64; ++t) {
        const int p = t & 1;
        float* h0b = h0x + p * 16384 + b * 256;
        float* h1b = h1x + p * 32768 + b * 512;
        float* hcb = hcx + p * 16384 + b * 256;
        // D1 (split): own 32 rows of dw1[:,0:512)
        {
            const int l = w * 4 + g4;
            const int j = coB + l;
            H8 a0, a1, a2, a3;
            a0.u = *(const uint4*)((const __half*)aHC + 8 * q16);
            a1.u = *(const uint4*)((const __half*)aHC + 8 * q16 + 128);
            a2.u = *(const uint4*)((const __half*)aHC + 8 * q16 + 256);
            a3.u = *(const uint4*)((const __half*)aHC + 8 * q16 + 384);
            const uint4* wp = (const uint4*)(RDW1 + ((size_t)j << 9) + 32 * q16);
            H8 w0, w1, w2, w3;
            w0.u = wp[0]; w1.u = wp[1]; w2.u = wp[2]; w3.u = wp[3];
            float s0 = 0.f, s1 = 0.f;
            #pragma unroll
            for (int i = 0; i < 4; ++i) {
                s0 = dot2h(w0.h[i], a0.h[i], s0);
                s1 = dot2h(w1.h[i], a1.h[i], s1);
                s0 = dot2h(w2.h[i], a2.h[i], s0);
                s1 = dot2h(w3.h[i], a3.h[i], s1);
            }
            float s = red16(s0 + s1);
            if (q16 == 0) tmp32[l] = s;
        }
        __syncthreads();
        if (tid < 32) atomicExch(&hcb[coB + tid], tmp32[tid]);
        xsig(ctr); ++ph;
        xwait(ctr, ph * 8u);
        if (tid < 256) hctL[tid] = exr(&hcb[tid]);
        __syncthreads();
        // D2: score[t']
        {
            float s = 0.f;
            #pragma unroll 8
            for (int jj = 0; jj < 32; ++jj) {
                int j = q8 + 8 * jj;
                s += tanhf_((float)PdL16[e8 * 256 + j] + hctL[j]) * w2dL[j];
            }
            s = red8(s);
            if (q8 == 0) scoreS[e8] = s;
        }
        __syncthreads();
        // D3: softmax -> aS
        if (tid < 64) {
            float v = scoreS[tid], m = v;
            #pragma unroll
            for (int d = 1; d < 64; d <<= 1) m = fmaxf(m, __shfl_xor(m, d));
            float ex = __expf(v - m), s = ex;
            #pragma unroll
            for (int d = 1; d < 64; d <<= 1) s += __shfl_xor(s, d);
            aS[tid] = ex / s;
        }
        __syncthreads();
        // D4 (replicated): partial[c] = sum_t' hexp16[t'][c] * a[t']
        if (tid < 256) {
            float acc = 0.f;
            #pragma unroll 8
            for (int tt = 0; tt < 64; ++tt)
                acc += (float)hexp16[tt * 256 + tid] * aS[tt];
            partF[tid] = acc;
            aD0[tid] = __float2half(acc);
        }
        __syncthreads();
        // D5 (split): layer0 gates (+ d_t column)
        gemvS512<4, true, true>(RD0, aD0, bD0f, rdtH, decin[t], gsl, coB);
        __syncthreads();
        // D6: elementwise l0 -> exchange h0
        if (tid < 32) {
            float cn = sigf(gsl[32 + tid]) * c0L[tid] + sigf(gsl[tid]) * tanhf_(gsl[64 + tid]);
            float hn = sigf(gsl[96 + tid]) * tanhf_(cn);
            c0L[tid] = cn;
            atomicExch(&h0b[coB + tid], hn);
        }
        xsig(ctr); ++ph;
        xwait(ctr, ph * 8u);
        if (tid < 256) {
            __half hh = __float2half(exr(&h0b[tid]));
            aD0[256 + tid] = hh; aHH[tid] = hh;
        }
        __syncthreads();
        // D7 (split): layer1 gates
        gemvS512<4, true, false>(RD1, aHH, bD1f, nullptr, 0.f, gsl, coB);
        __syncthreads();
        // D8: elementwise l1 -> exchange h1,c1
        if (tid < 32) {
            float cn = sigf(gsl[32 + tid]) * c1L[tid] + sigf(gsl[tid]) * tanhf_(gsl[64 + tid]);
            float hn = sigf(gsl[96 + tid]) * tanhf_(cn);
            c1L[tid] = cn;
            atomicExch(&h1b[coB + tid], hn);
            atomicExch(&h1b[256 + coB + tid], cn);
        }
        xsig(ctr); ++ph;
        xwait(ctr, ph * 8u);
        if (tid < 512) {
            float v = exr(&h1b[tid]);
            __half hh = __float2half(v);
            aHC[tid] = hh;
            if (tid < 256) { aHH[256 + tid] = hh; hc1f[tid] = v; }
        }
        __syncthreads();
    }

    // ---- output (one block per b) ----
    if (co == 0 && tid < 64) {
        float acc = 0.f;
        #pragma unroll
        for (int i = 0; i < 8; ++i) {
            int k = tid + 64 * i;
            float v = (k < 256) ? hc1f[k] : partF[k - 256];
            acc += v * pw[k];
        }
        acc = red64(acc);
        if (tid == 0) out[b] = fabsf(acc + pb[0]);
    }
}

// ---- fp16 permuted repack (v5 layout + RPD Pd tile) ----
extern "C" __global__ void repack16c(const float* __restrict__ wihe0,
                                     const float* __restrict__ wihe1,
                                     const float* __restrict__ whhe,
                                     const float* __restrict__ wihd0,
                                     const float* __restrict__ wihd1,
                                     const float* __restrict__ whhd,
                                     const float* __restrict__ aw1,
                                     const float* __restrict__ dw1,
                                     __half* __restrict__ ws) {
    int idx = blockIdx.x * blockDim.x + threadIdx.x;
    if (idx >= TOT_H2) return;
    int o = idx; float v;
    if (o < 32768) {
        int j = o >> 9, p = o & 511;
        int q = p >> 5, r = p & 31, c = r >> 3, e = r & 7;
        int k = 8 * q + 128 * c + e;
        v = aw1[j * 576 + k];
        ws[OFF_RA + o] = __float2half_rn(v); return;
    }
    o -= 32768;
    if (o < 393216) {
        int j = o / 384, p = o - j * 384;
        int q = p / 24, r = p - q * 24, c = r >> 3, e = r & 7;
        int k = 8 * q + 128 * c + e;
        v = (k < 64) ? wihe0[j * 64 + k] : (k < 320 ? whhe[j * 256 + (k - 64)] : 0.0f);
        ws[OFF_RE0 + o] = __float2half_rn(v); return;
    }
    o -= 393216;
    if (o < 524288) {
        int j = o >> 9, p = o & 511;
        int q = p >> 5, r = p & 31, c = r >> 3, e = r & 7;
        int k = 8 * q + 128 * c + e;
        v = (k < 256) ? wihe1[j * 256 + k] : whhe[262144 + j * 256 + (k - 256)];
        ws[OFF_RE1 + o] = __float2half_rn(v); return;
    }
    o -= 524288;
    if (o < 131072) {
        int j = o >> 9, p = o & 511;
        int q = p >> 5, r = p & 31, c = r >> 3, e = r & 7;
        int k = 8 * q + 128 * c + e;
        v = dw1[j * 768 + k];
        ws[OFF_RDW1 + o] = __float2half_rn(v); return;
    }
    o -= 131072;
    if (o < 524288) {
        int j = o >> 9, p = o & 511;
        int q = p >> 5, r = p & 31, c = r >> 3, e = r & 7;
        int k = 8 * q + 128 * c + e;
        v = (k < 256) ? wihd0[j * 257 + k] : whhd[j * 256 + (k - 256)];
        ws[OFF_RD0 + o] = __float2half_rn(v); return;
    }
    o -= 524288;
    if (o < 1024) {
        v = wihd0[o * 257 + 256];
        ws[OFF_RDT + o] = __float2half_rn(v); return;
    }
    o -= 1024;
    if (o < 524288) {
        int j = o >> 9, p = o & 511;
        int q = p >> 5, r = p & 31, c = r >> 3, e = r & 7;
        int k = 8 * q + 128 * c + e;
        v = (k < 256) ? wihd1[j * 256 + k] : whhd[262144 + j * 256 + (k - 256)];
        ws[OFF_RD1 + o] = __float2half_rn(v); return;
    }
    o -= 524288;
    {   // RPD: 256 x 256, packed[j][16q+8c+e] = dw1[j][512 + 8q+128c+e]
        int j = o >> 8, p = o & 255;
        int q = p >> 4, r = p & 15, c = r >> 3, e = r & 7;
        int k = 8 * q + 128 * c + e;
        v = dw1[j * 768 + 512 + k];
        ws[OFF_RPD + o] = __float2half_rn(v);
    }
}

// ======================= v5 fallback (tiny ws) =============================
template<int ITERS, bool BIAS, bool DT>
__device__ __forceinline__ void gemv512f(const __half* __restrict__ W,
                                         const __half* __restrict__ act,
                                         const float* __restrict__ bias,
                                         const __half* __restrict__ rdt, float dts,
                                         float* __restrict__ outg, int rowBase) {
    const int lane = threadIdx.x & 63;
    const int q = lane & 15, g = lane >> 4;
    H8 a0, a1, a2, a3;
    a0.u = *(const uint4*)(act + 8 * q);
    a1.u = *(const uint4*)(act + 8 * q + 128);
    a2.u = *(const uint4*)(act + 8 * q + 256);
    a3.u = *(const uint4*)(act + 8 * q + 384);
    #pragma unroll 2
    for (int it = 0; it < ITERS; ++it) {
        const int j = rowBase + it * 4 + g;
        const uint4* wp = (const uint4*)(W + ((size_t)j << 9) + 32 * q);
        H8 w0, w1, w2, w3;
        w0.u = wp[0]; w1.u = wp[1]; w2.u = wp[2]; w3.u = wp[3];
        float s0 = 0.f, s1 = 0.f;
        #pragma unroll
        for (int i = 0; i < 4; ++i) {
            s0 = dot2h(w0.h[i], a0.h[i], s0);
            s1 = dot2h(w1.h[i], a1.h[i], s1);
            s0 = dot2h(w2.h[i], a2.h[i], s0);
            s1 = dot2h(w3.h[i], a3.h[i], s1);
        }
        float s = red16(s0 + s1);
        if (q == 0) {
            if (DT) s += dts * (float)rdt[j];
            outg[j] = BIAS ? s + bias[j] : s;
        }
    }
}
template<int ITERS>
__device__ __forceinline__ void gemv384f(const __half* __restrict__ W,
                                         const __half* __restrict__ act,
                                         const float* __restrict__ bias,
                                         float* __restrict__ outg, int rowBase) {
    const int lane = threadIdx.x & 63;
    const int q = lane & 15, g = lane >> 4;
    H8 a0, a1, a2;
    a0.u = *(const uint4*)(act + 8 * q);
    a1.u = *(const uint4*)(act + 8 * q + 128);
    a2.u = *(const uint4*)(act + 8 * q + 256);
    #pragma unroll 2
    for (int it = 0; it < ITERS; ++it) {
        const int j = rowBase + it * 4 + g;
        const h2v* hp = (const h2v*)(W + (size_t)j * 384 + 24 * q);
        float s0 = 0.f, s1 = 0.f;
        #pragma unroll
        for (int i = 0; i < 4; ++i) s0 = dot2h(hp[i],     a0.h[i], s0);
        #pragma unroll
        for (int i = 0; i < 4; ++i) s1 = dot2h(hp[4 + i], a1.h[i], s1);
        #pragma unroll
        for (int i = 0; i < 4; ++i) s0 = dot2h(hp[8 + i], a2.h[i], s0);
        float s = red16(s0 + s1);
        if (q == 0) outg[j] = s + bias[j];
    }
}

#define L_HEXP   0
#define L_XET    16384
#define L_GSL    20736
#define L_HCT    21760
#define L_SCORE  22016
#define L_AS     22080
#define L_C0     22144
#define L_HC1F   22400
#define L_DECIN  22912
#define L_PARTF  22976
#define L_BE0    23232
#define L_BE1    24256
#define L_BD0    25280
#define L_BD1    26304
#define L_AHC    27328
#define L_AE0    27584
#define L_AHH    27776
#define L_AD0    28032
#define L_RDT    28288
#define L_TOT    28800

extern "C" __global__ void __launch_bounds__(NT)
attn_lstm_v5(const float* __restrict__ inp,  const __half* __restrict__ wsh,
             const float* __restrict__ bihe, const float* __restrict__ bhhe,
             const float* __restrict__ bihd, const float* __restrict__ bhhd,
             const float* __restrict__ aw1,  const float* __restrict__ ab1,
             const float* __restrict__ aw2,
             const float* __restrict__ dw1,  const float* __restrict__ db1,
             const float* __restrict__ dw2,
             const float* __restrict__ pw,   const float* __restrict__ pb,
             float* __restrict__ out)
{
    extern __shared__ __align__(16) float sm[];
    float* hexp   = sm + L_HEXP;
    float* xeT    = sm + L_XET;
    float* gsl    = sm + L_GSL;
    float* hctL   = sm + L_HCT;
    float* scoreS = sm + L_SCORE;
    float* aS     = sm + L_AS;
    float* c0L    = sm + L_C0;
    float* hc1f   = sm + L_HC1F;
    float* decin  = sm + L_DECIN;
    float* partF  = sm + L_PARTF;
    float* bE0    = sm + L_BE0;
    float* bE1    = sm + L_BE1;
    float* bD0    = sm + L_BD0;
    float* bD1    = sm + L_BD1;
    __half* aHC   = (__half*)(sm + L_AHC);
    __half* aE0   = (__half*)(sm + L_AE0);
    __half* aHH   = (__half*)(sm + L_AHH);
    __half* aD0   = (__half*)(sm + L_AD0);
    __half* rdtL  = (__half*)(sm + L_RDT);

    const __half* RA   = wsh + OFF_RA;
    const __half* RE0  = wsh + OFF_RE0;
    const __half* RE1  = wsh + OFF_RE1;
    const __half* RDW1 = wsh + OFF_RDW1;
    const __half* RD0  = wsh + OFF_RD0;
    const __half* RD1  = wsh + OFF_RD1;

    const int b   = blockIdx.x;
    const int tid = threadIdx.x;
    const int w   = tid >> 6;

    for (int i = tid; i < (L_BE0 - L_C0); i += NT) sm[L_C0 + i] = 0.0f;
    for (int i = tid; i < (L_RDT - L_AHC); i += NT) sm[L_AHC + i] = 0.0f;
    if (tid < 512) sm[L_RDT + tid] = ((const float*)(wsh + OFF_RDT))[tid];
    {
        int j = tid;
        bE0[j] = bihe[j]        + bhhe[j];
        bE1[j] = bihe[1024 + j] + bhhe[1024 + j];
        bD0[j] = bihd[j]        + bhhd[j];
        bD1[j] = bihd[1024 + j] + bhhd[1024 + j];
    }
    const float* ib = inp + b * (64 * 65);
    for (int i = tid; i < 4096; i += NT) {
        int t = i & 63, e = i >> 6;
        xeT[e * 68 + t] = ib[t * 65 + 1 + e];
    }
    if (tid < 64) decin[tid] = ib[tid * 65];
    __syncthreads();

    const int g16 = tid >> 4, q16 = tid & 15;

    float Preg[4], w2r[4];
    #pragma unroll
    for (int jj = 0; jj < 4; ++jj) {
        int j = q16 + 16 * jj;
        w2r[jj] = aw2[j];
        float acc = ab1[j];
        const float4* w4 = (const float4*)(aw1 + j * 576 + 512);
        const float4* x4 = (const float4*)(xeT + g16 * 68);
        #pragma unroll 4
        for (int k = 0; k < 16; ++k) acc += dot4(w4[k], x4[k]);
        Preg[jj] = acc;
    }

    for (int t = 0; t < 64; ++t) {
        gemv512f<1, false, false>(RA, aHC, nullptr, nullptr, 0.f, hctL, w * 4);
        __syncthreads();
        {
            float s = 0.f;
            #pragma unroll
            for (int jj = 0; jj < 4; ++jj)
                s += tanhf_(Preg[jj] + hctL[q16 + 16 * jj]) * w2r[jj];
            s = red16(s);
            if (q16 == 0) scoreS[g16] = s;
        }
        __syncthreads();
        if (tid < 64) {
            float v = scoreS[tid], m = v;
            #pragma unroll
            for (int d = 1; d < 64; d <<= 1) m = fmaxf(m, __shfl_xor(m, d));
            float ex = __expf(v - m), s = ex;
            #pragma unroll
            for (int d = 1; d < 64; d <<= 1) s += __shfl_xor(s, d);
            aE0[tid] = __float2half((ex / s) * xeT[tid * 68 + t]);
        }
        __syncthreads();
        gemv384f<16>(RE0, aE0, bE0, gsl, w * 64);
        __syncthreads();
        if (tid < 256) {
            float cn = sigf(gsl[256 + tid]) * c0L[tid] + sigf(gsl[tid]) * tanhf_(gsl[512 + tid]);
            float hn = sigf(gsl[768 + tid]) * tanhf_(cn);
            c0L[tid] = cn;
            __half hh = __float2half(hn);
            aE0[64 + tid] = hh; aHH[tid] = hh;
        }
        __syncthreads();
        gemv512f<16, true, false>(RE1, aHH, bE1, nullptr, 0.f, gsl, w * 64);
        __syncthreads();
        if (tid < 256) {
            float cp = hc1f[256 + tid];
            float cn = sigf(gsl[256 + tid]) * cp + sigf(gsl[tid]) * tanhf_(gsl[512 + tid]);
            float hn = sigf(gsl[768 + tid]) * tanhf_(cn);
            hc1f[tid] = hn; hc1f[256 + tid] = cn;
            __half hh = __float2half(hn);
            aHC[tid] = hh; aHC[256 + tid] = __float2half(cn);
            aHH[256 + tid] = hh;
            hexp[t * 256 + tid] = hn;
        }
        __syncthreads();
    }

    if (tid < 256) { c0L[tid] = 0.0f; hc1f[tid] = 0.0f; hc1f[256 + tid] = 0.0f; }
    for (int i = tid; i < (L_RDT - L_AHC); i += NT) sm[L_AHC + i] = 0.0f;
    __syncthreads();
    float Pdreg[16], w2dr[16];
    #pragma unroll
    for (int jj = 0; jj < 16; ++jj) {
        int j = q16 + 16 * jj;
        w2dr[jj] = dw2[j];
        float acc = db1[j];
        const float4* w4 = (const float4*)(dw1 + j * 768 + 512);
        const float4* x4 = (const float4*)(hexp + g16 * 256);
        #pragma unroll 4
        for (int k = 0; k < 64; ++k) acc += dot4(w4[k], x4[k]);
        Pdreg[jj] = acc;
    }
    __syncthreads();

    const int j4 = tid >> 2, q4 = tid & 3;
    for (int t = 0; t < 64; ++t) {
        gemv512f<4, false, false>(RDW1, aHC, nullptr, nullptr, 0.f, hctL, w * 16);
        __syncthreads();
        {
            float s = 0.f;
            #pragma unroll
            for (int jj = 0; jj < 16; ++jj)
                s += tanhf_(Pdreg[jj] + hctL[q16 + 16 * jj]) * w2dr[jj];
            s = red16(s);
            if (q16 == 0) scoreS[g16] = s;
        }
        __syncthreads();
        if (tid < 64) {
            float v = scoreS[tid], m = v;
            #pragma unroll
            for (int d = 1; d < 64; d <<= 1) m = fmaxf(m, __shfl_xor(m, d));
            float ex = __expf(v - m), s = ex;
            #pragma unroll
            for (int d = 1; d < 64; d <<= 1) s += __shfl_xor(s, d);
            aS[tid] = ex / s;
        }
        __syncthreads();
        {
            float acc = 0.f;
            #pragma unroll 4
            for (int i = 0; i < 16; ++i) {
                int tt = q4 + 4 * i;
                acc += hexp[tt * 256 + j4] * aS[tt];
            }
            acc += __shfl_xor(acc, 1);
            acc += __shfl_xor(acc, 2);
            if (q4 == 0) { aD0[j4] = __float2half(acc); partF[j4] = acc; }
        }
        __syncthreads();
        gemv512f<16, true, true>(RD0, aD0, bD0, rdtL, decin[t], gsl, w * 64);
        __syncthreads();
        if (tid < 256) {
            float cn = sigf(gsl[256 + tid]) * c0L[tid] + sigf(gsl[tid]) * tanhf_(gsl[512 + tid]);
            float hn = sigf(gsl[768 + tid]) * tanhf_(cn);
            c0L[tid] = cn;
            __half hh = __float2half(hn);
            aD0[256 + tid] = hh; aHH[tid] = hh;
        }
        __syncthreads();
        gemv512f<16, true, false>(RD1, aHH, bD1, nullptr, 0.f, gsl, w * 64);
        __syncthreads();
        if (tid < 256) {
            float cp = hc1f[256 + tid];
            float cn = sigf(gsl[256 + tid]) * cp + sigf(gsl[tid]) * tanhf_(gsl[512 + tid]);
            float hn = sigf(gsl[768 + tid]) * tanhf_(cn);
            hc1f[tid] = hn; hc1f[256 + tid] = cn;
            __half hh = __float2half(hn);
            aHC[tid] = hh; aHC[256 + tid] = __float2half(cn);
            aHH[256 + tid] = hh;
        }
        __syncthreads();
    }

    if (tid < 64) {
        float acc = 0.f;
        #pragma unroll
        for (int i = 0; i < 8; ++i) {
            int k = tid + 64 * i;
            float v = (k < 256) ? hc1f[k] : partF[k - 256];
            acc += v * pw[k];
        }
        acc = red64(acc);
        if (tid == 0) out[b] = fabsf(acc + pb[0]);
    }
}

extern "C" void kernel_launch(void* const* d_in, const int* in_sizes, int n_in,
                              void* d_out, int out_size, void* d_ws, size_t ws_size,
                              hipStream_t stream) {
    const float* inp   = (const float*)d_in[0];
    const float* wihe0 = (const float*)d_in[1];
    const float* wihe1 = (const float*)d_in[2];
    const float* whhe  = (const float*)d_in[3];
    const float* bihe  = (const float*)d_in[4];
    const float* bhhe  = (const float*)d_in[5];
    const float* wihd0 = (const float*)d_in[6];
    const float* wihd1 = (const float*)d_in[7];
    const float* whhd  = (const float*)d_in[8];
    const float* bihd  = (const float*)d_in[9];
    const float* bhhd  = (const float*)d_in[10];
    const float* aw1   = (const float*)d_in[11];
    const float* ab1   = (const float*)d_in[12];
    const float* aw2   = (const float*)d_in[13];
    const float* dw1   = (const float*)d_in[14];
    const float* db1   = (const float*)d_in[15];
    const float* dw2   = (const float*)d_in[16];
    const float* pw    = (const float*)d_in[17];
    const float* pb    = (const float*)d_in[18];
    float* out = (float*)d_out;

    // ws layout (float offsets): fp16 weights occupy [0, TOT_H2/2)
    const size_t EX0 = TOT_H2 / 2;           // 1,098,240
    const size_t H0X = EX0;                  // 2*64*256 = 32768
    const size_t H1X = EX0 + 32768;          // 2*64*512 = 65536
    const size_t HCX = EX0 + 98304;          // 2*64*256 = 32768
    const size_t CTR = EX0 + 131072;         // 64 groups * 16 uints
    const size_t NEED8 = (CTR + 1024) * sizeof(float);

    if (ws_size >= NEED8) {
        float* ws32 = (float*)d_ws;
        __half* wsh = (__half*)d_ws;
        hipMemsetAsync((char*)d_ws + CTR * sizeof(float), 0, 4096, stream);
        repack16c<<<(TOT_H2 + 255) / 256, 256, 0, stream>>>(
            wihe0, wihe1, whhe, wihd0, wihd1, whhd, aw1, dw1, wsh);
        const int smem = V8_TOT * 4;   // 77,440 B -> 2 blocks/CU
        hipFuncSetAttribute((const void*)attn_lstm_v8,
                            hipFuncAttributeMaxDynamicSharedMemorySize, smem);
        attn_lstm_v8<<<512, NT8, smem, stream>>>(
            inp, wsh, ws32 + H0X, ws32 + H1X, ws32 + HCX,
            (unsigned*)(ws32 + CTR),
            bihe, bhhe, bihd, bhhd,
            aw1, ab1, aw2, db1, dw2, pw, pb, out);
        return;
    }

    // fallback: v5 single-block-per-batch (needs only the weight region)
    if (ws_size >= (size_t)TOT_H2 * sizeof(__half)) {
        __half* wsh = (__half*)d_ws;
        repack16c<<<(TOT_H2 + 255) / 256, 256, 0, stream>>>(
            wihe0, wihe1, whhe, wihd0, wihd1, whhd, aw1, dw1, wsh);
        const int smem = L_TOT * 4;
        hipFuncSetAttribute((const void*)attn_lstm_v5,
                            hipFuncAttributeMaxDynamicSharedMemorySize, smem);
        attn_lstm_v5<<<64, NT, smem, stream>>>(
            inp, wsh, bihe, bhhe, bihd, bhhd,
            aw1, ab1, aw2, dw1, db1, dw2, pw, pb, out);
    }
}